// Round 5
// baseline (93.919 us; speedup 1.0000x reference)
//
#include <hip/hip_runtime.h>

#define IN_F 4096
#define OUT_F 11008
#define M 8
#define S_SLICES 16
#define KPS (IN_F / S_SLICES)     // 256 k-values per slice
#define RPSL (KPS / 8)            // 32 packed qweight rows per slice
#define STEPS (KPS / 32)          // 8 MFMA K-steps per slice

typedef __bf16 bf16x8 __attribute__((ext_vector_type(8)));
typedef float  f32x4  __attribute__((ext_vector_type(4)));
typedef unsigned int u32x4 __attribute__((ext_vector_type(4)));

// pack two fp32 into one VGPR of 2 bf16 (truncation; exact for small ints)
__device__ __forceinline__ unsigned pack_bf(float lo, float hi) {
    return (__float_as_uint(lo) >> 16) | (__float_as_uint(hi) & 0xffff0000u);
}

// ---------------- fused MFMA partial GEMM ----------------
// P[slice][r][col] = sum_{k in slice} (w[k][col] - z[col]) * x_bf16[r][k]
// Layouts (round-4 verified on-HW): A[m=lane&15][k=quad*8+j] (j = vector elem);
// B[k=quad*8+j][n=lane&15] where the k-run of 8 == LSB-first nibbles of ONE
// qweight int32; D[row=quad*4+reg][col=lane&15].
__global__ __launch_bounds__(256) void gptq_mfma_kernel(
    const float* __restrict__ x,    // (M, IN_F) fp32
    const int*   __restrict__ qw,   // (512, OUT_F)
    const int*   __restrict__ qz,   // (1, OUT_F/8)
    float*       __restrict__ P)    // (S_SLICES, M, OUT_F)
{
    const int lane = threadIdx.x & 63;
    const int wv   = threadIdx.x >> 6;                 // wave 0..3
    const int t    = lane & 15;                        // = m (A) = n (B) = col (D)
    const int quad = lane >> 4;                        // 0..3
    const int col  = (blockIdx.x * 4 + wv) * 16 + t;   // 172*4*16 = 11008 exact
    const int i0   = blockIdx.y * RPSL;                // first packed row of slice
    const int kb   = blockIdx.y * KPS;                 // first k of slice

    // per-column zero point (per-lane constant), GPTQ +1 convention
    const int zi = ((qz[col >> 3] >> ((col & 7) * 4)) & 15) + 1;

    // ---- issue all slice loads up front ----
    int qv[STEPS];
    const int* qcol = qw + (size_t)(i0 + quad) * OUT_F + col;
#pragma unroll
    for (int s = 0; s < STEPS; ++s)
        qv[s] = qcol[(size_t)s * 4 * OUT_F];           // row i0 + s*4 + quad

    // A fragments: fp32 x loaded + truncate-packed in-register.
    // Lanes with t >= M feed the zero-pad rows 8..15 (no load).
    union AF { u32x4 u; bf16x8 v; } afr[STEPS];
    const float* xrow = x + (size_t)t * IN_F + kb + quad * 8;
#pragma unroll
    for (int s = 0; s < STEPS; ++s) {
        if (t < M) {
            const float4 a = *(const float4*)(xrow + s * 32);
            const float4 b = *(const float4*)(xrow + s * 32 + 4);
            afr[s].u[0] = pack_bf(a.x, a.y);
            afr[s].u[1] = pack_bf(a.z, a.w);
            afr[s].u[2] = pack_bf(b.x, b.y);
            afr[s].u[3] = pack_bf(b.z, b.w);
        } else {
            afr[s].u = (u32x4)(0u);
        }
    }

    f32x4 acc = {0.f, 0.f, 0.f, 0.f};
#pragma unroll
    for (int s = 0; s < STEPS; ++s) {
        union { u32x4 u; bf16x8 v; } bf;
        const int q = qv[s];
#pragma unroll
        for (int w = 0; w < 4; ++w) {
            const int n0 = ((q >> (8 * w))     & 15) - zi;  // exact int in bf16
            const int n1 = ((q >> (8 * w + 4)) & 15) - zi;
            bf.u[w] = pack_bf((float)n0, (float)n1);
        }
        acc = __builtin_amdgcn_mfma_f32_16x16x32_bf16(afr[s].v, bf.v, acc, 0, 0, 0);
    }

    // D rows 0..7 are the real x-rows (quads 0,1); rows 8..15 are the zero-pad.
    const int r0 = quad * 4;
    if (r0 < M) {
        float* Pp = P + (size_t)blockIdx.y * (M * OUT_F);
#pragma unroll
        for (int r = 0; r < 4; ++r)
            Pp[(size_t)(r0 + r) * OUT_F + col] = acc[r];
    }
}

// ---------------- out[r][j] = bias[j] + s_j * sum_s P[s][r][j] ----------------
__global__ __launch_bounds__(256) void epilogue_kernel(
    const float* __restrict__ P, const float* __restrict__ sc,
    const float* __restrict__ bias, float* __restrict__ out)
{
    const int idx = blockIdx.x * 256 + threadIdx.x;   // 0 .. M*OUT_F-1
    const int j = idx % OUT_F;
    const int r = idx / OUT_F;

    float acc = 0.0f;
#pragma unroll
    for (int s = 0; s < S_SLICES; ++s)
        acc += P[(size_t)s * M * OUT_F + (size_t)r * OUT_F + j];

    out[(size_t)r * OUT_F + j] = fmaf(sc[j], acc, bias[j]);
}

extern "C" void kernel_launch(void* const* d_in, const int* in_sizes, int n_in,
                              void* d_out, int out_size, void* d_ws, size_t ws_size,
                              hipStream_t stream) {
    const float* x    = (const float*)d_in[0];
    const int*   qw   = (const int*)d_in[1];
    const int*   qz   = (const int*)d_in[2];
    const float* sc   = (const float*)d_in[3];
    const float* bias = (const float*)d_in[4];
    float* out = (float*)d_out;

    float* P = (float*)d_ws;   // S_SLICES * M * OUT_F floats = 5.6 MB

    hipLaunchKernelGGL(gptq_mfma_kernel, dim3(OUT_F / 64, S_SLICES), dim3(256), 0, stream,
                       x, qw, qz, P);
    hipLaunchKernelGGL(epilogue_kernel, dim3((M * OUT_F) / 256), dim3(256), 0, stream,
                       P, sc, bias, out);
}

// Round 6
// 92.808 us; speedup vs baseline: 1.0120x; 1.0120x over previous
//
#include <hip/hip_runtime.h>

#define IN_F 4096
#define OUT_F 11008
#define M 8
#define S_SLICES 16
#define KPS (IN_F / S_SLICES)     // 256 k-values per slice
#define RPSL (KPS / 8)            // 32 packed qweight rows per slice
#define STEPS (KPS / 32)          // 8 MFMA K-steps per slice

typedef __bf16 bf16x8 __attribute__((ext_vector_type(8)));
typedef float  f32x4  __attribute__((ext_vector_type(4)));
typedef unsigned int u32x4 __attribute__((ext_vector_type(4)));

// pack two fp32 into one VGPR of 2 bf16 (truncation; exact for small ints)
__device__ __forceinline__ unsigned pack_bf(float lo, float hi) {
    return (__float_as_uint(lo) >> 16) | (__float_as_uint(hi) & 0xffff0000u);
}

// ---------------- out[r][j] = bias[j]  (out is 0xAA-poisoned before every launch) ----------------
__global__ __launch_bounds__(256) void init_out_kernel(
    const float* __restrict__ bias, float* __restrict__ out)
{
    const int idx = blockIdx.x * 256 + threadIdx.x;   // 0 .. M*OUT_F-1
    out[idx] = bias[idx % OUT_F];
}

// ---------------- fused MFMA GEMM, atomic accumulate into out ----------------
// out[r][col] += sc[col] * sum_{k in slice} (w[k][col] - z[col]) * x_bf16[r][k]
// Layouts (HW-verified rounds 4-5): A[m=lane&15][k=quad*8+j]; B[k=quad*8+j][n=lane&15]
// where the k-run of 8 == LSB-first nibbles of ONE qweight int32; D[row=quad*4+reg][col=lane&15].
__global__ __launch_bounds__(256) void gptq_mfma_kernel(
    const float* __restrict__ x,    // (M, IN_F) fp32
    const int*   __restrict__ qw,   // (512, OUT_F)
    const int*   __restrict__ qz,   // (1, OUT_F/8)
    const float* __restrict__ sc,   // (1, OUT_F)
    float*       __restrict__ out)  // (M, OUT_F), pre-initialized with bias
{
    const int lane = threadIdx.x & 63;
    const int wv   = threadIdx.x >> 6;                 // wave 0..3
    const int t    = lane & 15;                        // = m (A) = n (B) = col (D)
    const int quad = lane >> 4;                        // 0..3
    const int col  = (blockIdx.x * 4 + wv) * 16 + t;   // 172*4*16 = 11008 exact
    const int i0   = blockIdx.y * RPSL;                // first packed row of slice
    const int kb   = blockIdx.y * KPS;                 // first k of slice

    // per-column zero point (per-lane constant), GPTQ +1 convention
    const int zi = ((qz[col >> 3] >> ((col & 7) * 4)) & 15) + 1;

    // ---- issue all slice loads up front (8 qw + 8 x-frag pairs in flight) ----
    int qv[STEPS];
    const int* qcol = qw + (size_t)(i0 + quad) * OUT_F + col;
#pragma unroll
    for (int s = 0; s < STEPS; ++s)
        qv[s] = qcol[(size_t)s * 4 * OUT_F];           // row i0 + s*4 + quad

    // A fragments: fp32 x loaded + truncate-packed in-register.
    // Lanes with t >= M feed the zero-pad rows 8..15 (no load).
    union AF { u32x4 u; bf16x8 v; } afr[STEPS];
    const float* xrow = x + (size_t)t * IN_F + kb + quad * 8;
#pragma unroll
    for (int s = 0; s < STEPS; ++s) {
        if (t < M) {
            const float4 a = *(const float4*)(xrow + s * 32);
            const float4 b = *(const float4*)(xrow + s * 32 + 4);
            afr[s].u[0] = pack_bf(a.x, a.y);
            afr[s].u[1] = pack_bf(a.z, a.w);
            afr[s].u[2] = pack_bf(b.x, b.y);
            afr[s].u[3] = pack_bf(b.z, b.w);
        } else {
            afr[s].u = (u32x4)(0u);
        }
    }

    f32x4 acc = {0.f, 0.f, 0.f, 0.f};
#pragma unroll
    for (int s = 0; s < STEPS; ++s) {
        union { u32x4 u; bf16x8 v; } bf;
        const int q = qv[s];
#pragma unroll
        for (int w = 0; w < 4; ++w) {
            const int n0 = ((q >> (8 * w))     & 15) - zi;  // exact int in bf16
            const int n1 = ((q >> (8 * w + 4)) & 15) - zi;
            bf.u[w] = pack_bf((float)n0, (float)n1);
        }
        acc = __builtin_amdgcn_mfma_f32_16x16x32_bf16(afr[s].v, bf.v, acc, 0, 0, 0);
    }

    // D rows 0..7 are real x-rows (quads 0,1); rows 8..15 are the zero-pad.
    const int r0 = quad * 4;
    if (r0 < M) {
        const float s = sc[col];
#pragma unroll
        for (int r = 0; r < 4; ++r)
            unsafeAtomicAdd(&out[(size_t)(r0 + r) * OUT_F + col], s * acc[r]);
    }
}

extern "C" void kernel_launch(void* const* d_in, const int* in_sizes, int n_in,
                              void* d_out, int out_size, void* d_ws, size_t ws_size,
                              hipStream_t stream) {
    const float* x    = (const float*)d_in[0];
    const int*   qw   = (const int*)d_in[1];
    const int*   qz   = (const int*)d_in[2];
    const float* sc   = (const float*)d_in[3];
    const float* bias = (const float*)d_in[4];
    float* out = (float*)d_out;

    hipLaunchKernelGGL(init_out_kernel, dim3((M * OUT_F) / 256), dim3(256), 0, stream,
                       bias, out);
    hipLaunchKernelGGL(gptq_mfma_kernel, dim3(OUT_F / 64, S_SLICES), dim3(256), 0, stream,
                       x, qw, qz, sc, out);
}